// Round 7
// baseline (432.468 us; speedup 1.0000x reference)
//
#include <hip/hip_runtime.h>

#define N_NODES 10000
#define E_EDGES 150000
#define KNB     15
#define FILL_BLOCKS 587   // ceil(E/256)
#define GEMM_BLOCKS 628   // 157 rowBlks x 4 colBlks

// ---------------------------------------------------------------------------
// gemm_tile2 (MR=2) — weight-space folds only
// ---------------------------------------------------------------------------
__device__ __forceinline__
void gemm_tile2(const float* __restrict__ A, int K,
                const float* __restrict__ Blo, const float* __restrict__ Bhi, int ldB,
                float* __restrict__ C, int ldC, int M,
                int rowBlk, int colBlk) {
    __shared__ float As2[16][34];
    __shared__ float Bs2[16][64];
    int tid = threadIdx.x;
    int tn  = tid & 15, tm = tid >> 4;
    int arow = tid >> 3, acB = (tid & 7) << 1;
    int brow = tid >> 4, bcol = (tid & 15) << 2;
    int rowBase = rowBlk * 32, colBase = colBlk * 64;

    bool half = (Bhi != nullptr) && (colBase >= 128);
    const float* B = half ? Bhi : Blo;
    int bj = colBase - (half ? 128 : 0) + bcol;

    float2 av; float4 bv;
    auto loadA = [&](int k0, float2& dst) {
        int gr = rowBase + arow;
        if (gr < M) dst = *(const float2*)(A + (size_t)gr * K + k0 + acB);
        else { dst.x = dst.y = 0.f; }
    };
    auto loadB = [&](int k0, float4& dst) {
        dst = *(const float4*)(B + (size_t)(k0 + brow) * ldB + bj);
    };
    loadA(0, av); loadB(0, bv);

    float acc[2][4] = {};
    for (int k0 = 0; k0 < K; k0 += 16) {
        __syncthreads();
        As2[acB + 0][arow] = av.x; As2[acB + 1][arow] = av.y;
        *(float4*)&Bs2[brow][bcol] = bv;
        __syncthreads();
        if (k0 + 16 < K) { loadA(k0 + 16, av); loadB(k0 + 16, bv); }
#pragma unroll
        for (int k = 0; k < 16; ++k) {
            float4 b = *(const float4*)&Bs2[k][tn << 2];
            float2 a = *(const float2*)&As2[k][tm << 1];
            acc[0][0] = fmaf(a.x, b.x, acc[0][0]); acc[0][1] = fmaf(a.x, b.y, acc[0][1]);
            acc[0][2] = fmaf(a.x, b.z, acc[0][2]); acc[0][3] = fmaf(a.x, b.w, acc[0][3]);
            acc[1][0] = fmaf(a.y, b.x, acc[1][0]); acc[1][1] = fmaf(a.y, b.y, acc[1][1]);
            acc[1][2] = fmaf(a.y, b.z, acc[1][2]); acc[1][3] = fmaf(a.y, b.w, acc[1][3]);
        }
    }
#pragma unroll
    for (int i = 0; i < 2; ++i) {
        int row = rowBase + tm * 2 + i;
        if (row >= M) continue;
#pragma unroll
        for (int j = 0; j < 4; ++j)
            C[(size_t)row * ldC + colBase + (tn << 2) + j] = acc[i][j];
    }
}

// ---------------------------------------------------------------------------
// Launch 1: block 0 = CSR histogram+scan (LDS hist, writes cnt/eoff/maskv and
// zeroes fillc); blocks 1..40 = weight folds (M1, M2, WH, v1, v2, bu2, bx2).
// ---------------------------------------------------------------------------
__global__ __launch_bounds__(256)
void scanfold_kernel(const int* __restrict__ idxs,
                     const float* __restrict__ mw2, const float* __restrict__ mb2,
                     const float* __restrict__ nw1, const float* __restrict__ nb2,
                     const float* __restrict__ nw2,
                     const float* __restrict__ m2w1, const float* __restrict__ m2b1,
                     const float* __restrict__ m2w2, const float* __restrict__ m2b2,
                     const float* __restrict__ n2w1, const float* __restrict__ n2b1,
                     float* __restrict__ M1, float* __restrict__ M2,
                     float* __restrict__ WH,
                     float* __restrict__ v1, float* __restrict__ v2,
                     float* __restrict__ bu2, float* __restrict__ bx2,
                     int* __restrict__ cnt, int* __restrict__ eoff,
                     float* __restrict__ maskv, int* __restrict__ fillc) {
    int b = blockIdx.x;
    if (b == 0) {
        __shared__ int hist[N_NODES];
        __shared__ int ssum[256];
        int tid = threadIdx.x;
        for (int i = tid; i < N_NODES; i += 256) hist[i] = 0;
        __syncthreads();
        for (int i = tid; i < E_EDGES; i += 256) atomicAdd(&hist[idxs[i]], 1);
        __syncthreads();
        const int CH = 40;                 // 256*40 = 10240 >= N
        int base = tid * CH, s = 0;
        for (int q = 0; q < CH; ++q) {
            int i = base + q;
            if (i < N_NODES) s += hist[i];
        }
        ssum[tid] = s;
        __syncthreads();
        for (int off = 1; off < 256; off <<= 1) {
            int v = (tid >= off) ? ssum[tid - off] : 0;
            __syncthreads();
            ssum[tid] += v;
            __syncthreads();
        }
        int ex = ssum[tid] - s;            // exclusive prefix of chunk
        for (int q = 0; q < CH; ++q) {
            int i = base + q;
            if (i < N_NODES) {
                int c = hist[i];
                cnt[i]   = c;
                eoff[i]  = ex;
                maskv[i] = (c > 0) ? 1.f : 0.f;
                fillc[i] = 0;
                ex += c;
            }
        }
        return;
    }
    b -= 1;
    if (b < 8) {
        gemm_tile2(mw2, 784, nw1 + 784 * 128, nullptr, 128, M1, 128, 128, b >> 1, b & 1);
    } else if (b < 16) {
        int t = b - 8;
        gemm_tile2(m2w2, 128, n2w1 + 128 * 128, nullptr, 128, M2, 128, 128, t >> 1, t & 1);
    } else if (b < 32) {
        int t = b - 16;
        gemm_tile2(nw2, 128, m2w1, n2w1, 128, WH, 256, 128, t >> 2, t & 3);
    } else {
        __shared__ float red[256];
        int t  = (b - 32) >> 1;
        int j  = ((b - 32) & 1) * 64 + (threadIdx.x & 63);
        int kq = threadIdx.x >> 6;
        const float* bvec; const float* Bv; const float* add; float* out; int Kv;
        if (t == 0)      { bvec = mb2;  Bv = nw1 + 784 * 128;  add = nullptr; out = v1;  Kv = 784; }
        else if (t == 1) { bvec = m2b2; Bv = n2w1 + 128 * 128; add = nullptr; out = v2;  Kv = 128; }
        else if (t == 2) { bvec = nb2;  Bv = m2w1;             add = m2b1;    out = bu2; Kv = 128; }
        else             { bvec = nb2;  Bv = n2w1;             add = n2b1;    out = bx2; Kv = 128; }
        float acc = 0.f;
        for (int k = kq; k < Kv; k += 4) acc = fmaf(bvec[k], Bv[k * 128 + j], acc);
        red[threadIdx.x] = acc;
        __syncthreads();
        if (threadIdx.x < 64) {
            float tot = red[threadIdx.x] + red[threadIdx.x + 64] +
                        red[threadIdx.x + 128] + red[threadIdx.x + 192];
            out[j] = tot + (add ? add[j] : 0.f);
        }
    }
}

// ---------------------------------------------------------------------------
// gemm784 tile — R3-proven structure: 256 thr, 64x64 tile, 4x4 micro,
// LDS A(transposed, pad 68) + B, register prefetch, 2 barriers/k-tile.
// ---------------------------------------------------------------------------
__device__ __forceinline__
void gemm784_tile(const float* __restrict__ A,
                  const float* __restrict__ B0, const float* __restrict__ B1,
                  const float* __restrict__ biasLo, const float* __restrict__ biasHi,
                  const float* __restrict__ vhi, const float* __restrict__ rowmask,
                  float* __restrict__ C, int M, int gb) {
    __shared__ float As[16][68];
    __shared__ float Bs[16][64];
    int rb = gb >> 2, cb = gb & 3;
    int tid = threadIdx.x;
    int tm = tid >> 4, tn = tid & 15;
    int arow = tid >> 2, ac4 = (tid & 3) << 2;
    int brow = tid >> 4, bc4 = (tid & 15) << 2;
    int rowBase = rb * 64, colBase = cb * 64;
    bool hi = colBase >= 128;
    const float* B    = hi ? B1 : B0;
    const float* bias = hi ? biasHi : biasLo;
    int bj = ((cb & 1) << 6) + bc4;

    int gr = rowBase + arow; if (gr > M - 1) gr = M - 1;   // clamp; stores guarded
    const float* Ap = A + (size_t)gr * 784;

    float4 av, bv;
    av = *(const float4*)(Ap + ac4);
    bv = *(const float4*)(B + (size_t)brow * 128 + bj);

    float acc[4][4] = {};
    for (int k0 = 0; k0 < 784; k0 += 16) {
        __syncthreads();
        As[ac4 + 0][arow] = av.x;
        As[ac4 + 1][arow] = av.y;
        As[ac4 + 2][arow] = av.z;
        As[ac4 + 3][arow] = av.w;
        *(float4*)&Bs[brow][bc4] = bv;
        __syncthreads();
        if (k0 + 16 < 784) {
            av = *(const float4*)(Ap + k0 + 16 + ac4);
            bv = *(const float4*)(B + (size_t)(k0 + 16 + brow) * 128 + bj);
        }
#pragma unroll
        for (int k = 0; k < 16; ++k) {
            float4 a = *(const float4*)&As[k][tm << 2];
            float4 b = *(const float4*)&Bs[k][tn << 2];
            acc[0][0] = fmaf(a.x, b.x, acc[0][0]); acc[0][1] = fmaf(a.x, b.y, acc[0][1]);
            acc[0][2] = fmaf(a.x, b.z, acc[0][2]); acc[0][3] = fmaf(a.x, b.w, acc[0][3]);
            acc[1][0] = fmaf(a.y, b.x, acc[1][0]); acc[1][1] = fmaf(a.y, b.y, acc[1][1]);
            acc[1][2] = fmaf(a.y, b.z, acc[1][2]); acc[1][3] = fmaf(a.y, b.w, acc[1][3]);
            acc[2][0] = fmaf(a.z, b.x, acc[2][0]); acc[2][1] = fmaf(a.z, b.y, acc[2][1]);
            acc[2][2] = fmaf(a.z, b.z, acc[2][2]); acc[2][3] = fmaf(a.z, b.w, acc[2][3]);
            acc[3][0] = fmaf(a.w, b.x, acc[3][0]); acc[3][1] = fmaf(a.w, b.y, acc[3][1]);
            acc[3][2] = fmaf(a.w, b.z, acc[3][2]); acc[3][3] = fmaf(a.w, b.w, acc[3][3]);
        }
    }

#pragma unroll
    for (int i = 0; i < 4; ++i) {
        int row = rowBase + (tm << 2) + i;
        if (row >= M) continue;
        float rm = hi ? rowmask[row] : 0.f;
#pragma unroll
        for (int j = 0; j < 4; ++j) {
            int gcol = colBase + (tn << 2) + j;
            int cj   = gcol & 127;
            float v = acc[i][j] + bias[cj];
            if (hi) v = fmaf(rm, vhi[cj], v);
            C[(size_t)row * 256 + gcol] = v;
        }
    }
}

// ---------------------------------------------------------------------------
// Launch 2: blocks [0,587) CSR fill; blocks [587,1215) gemm784.
// fill's memory-bound atomics overlap gemm's VALU work.
// ---------------------------------------------------------------------------
__global__ __launch_bounds__(256)
void fillgemm_kernel(const int* __restrict__ idxs, const float* __restrict__ ea,
                     const int* __restrict__ eoff, int* __restrict__ fillc,
                     float* __restrict__ eas,
                     const float* __restrict__ A,
                     const float* __restrict__ B0, const float* __restrict__ B1,
                     const float* __restrict__ biasLo, const float* __restrict__ biasHi,
                     const float* __restrict__ vhi, const float* __restrict__ rowmask,
                     float* __restrict__ C, int M) {
    int gb = blockIdx.x;
    if (gb < FILL_BLOCKS) {
        int i = gb * 256 + threadIdx.x;
        if (i < E_EDGES) {
            int s = idxs[i];
            int p = atomicAdd(&fillc[s], 1);
            eas[eoff[s] + p] = ea[i];
        }
        return;
    }
    gemm784_tile(A, B0, B1, biasLo, biasHi, vhi, rowmask, C, M, gb - FILL_BLOCKS);
}

// ---------------------------------------------------------------------------
// fused_mid (grid 313, 32 rows/block):
//  phase0: LDS-staged CSR edge window -> mhT[d][m] = mean_e relu(u + ea*w); rmask
//  phase1: ts[32][128] = relu(xn + mhT @ M1)        (4x4 micro)
//  phase2: UX2[32][256] = ts @ WH + bias (+rm*v2)   (4x8 micro)
// ---------------------------------------------------------------------------
__global__ __launch_bounds__(256)
void fused_mid_kernel(const float* __restrict__ UX, const float* __restrict__ wlast,
                      const float* __restrict__ eas, const int* __restrict__ eoff,
                      const int* __restrict__ cnt,
                      const float* __restrict__ Mmat, const float* __restrict__ WH,
                      const float* __restrict__ bu2, const float* __restrict__ bx2,
                      const float* __restrict__ v2,
                      float* __restrict__ UX2, int M) {
    __shared__ float mhT[128][36];
    __shared__ float ts[32][132];
    __shared__ float Bs[16][264];
    __shared__ float ebuf[1536];
    __shared__ float rmask[32];
    int rowBase = blockIdx.x * 32;
    int tid = threadIdx.x;

    // ---- phase 0 ----
    {
        int d = tid & 127, sub = tid >> 7;
        float w = wlast[d];
        float uu[16], sum[16];
        int es[16], ec[16];
#pragma unroll
        for (int it = 0; it < 16; ++it) {
            int n  = rowBase + it * 2 + sub;
            int nc = (n < M) ? n : M - 1;
            ec[it] = cnt[nc];
            es[it] = eoff[nc];
            uu[it] = UX[(size_t)nc * 256 + d];
            sum[it] = 0.f;
            if (d == 0) rmask[it * 2 + sub] = (ec[it] > 0) ? 1.f : 0.f;
        }
        int ebase = eoff[rowBase];
        int eend  = (rowBase + 32 < M) ? eoff[rowBase + 32] : E_EDGES;
        for (int w0 = ebase; w0 < eend; w0 += 1536) {
            int wlen = min(1536, eend - w0);
            __syncthreads();
            for (int q = tid; q < wlen; q += 256) ebuf[q] = eas[w0 + q];
            __syncthreads();
#pragma unroll
            for (int it = 0; it < 16; ++it) {
                int lo = max(es[it], w0), hi = min(es[it] + ec[it], w0 + wlen);
                for (int e = lo; e < hi; ++e)
                    sum[it] += fmaxf(fmaf(ebuf[e - w0], w, uu[it]), 0.f);
            }
        }
#pragma unroll
        for (int it = 0; it < 16; ++it)
            mhT[d][it * 2 + sub] = (ec[it] > 0) ? sum[it] / (float)ec[it] : 0.f;
    }
    __syncthreads();

    // ---- phase 1: ts = relu(xn + mhT @ Mmat) ----
    {
        int tm = tid >> 5, tn = tid & 31;
        float acc[4][4] = {};
        for (int k0 = 0; k0 < 128; k0 += 16) {
#pragma unroll
            for (int t2 = 0; t2 < 2; ++t2) {
                int f2 = (tid << 1) | t2;
                int kr = f2 >> 5, c4 = (f2 & 31) << 2;
                *(float4*)&Bs[kr][c4] = *(const float4*)(Mmat + (size_t)(k0 + kr) * 128 + c4);
            }
            __syncthreads();
#pragma unroll
            for (int k = 0; k < 16; ++k) {
                float4 a = *(const float4*)&mhT[k0 + k][tm << 2];
                float4 b = *(const float4*)&Bs[k][tn << 2];
                acc[0][0] = fmaf(a.x, b.x, acc[0][0]); acc[0][1] = fmaf(a.x, b.y, acc[0][1]);
                acc[0][2] = fmaf(a.x, b.z, acc[0][2]); acc[0][3] = fmaf(a.x, b.w, acc[0][3]);
                acc[1][0] = fmaf(a.y, b.x, acc[1][0]); acc[1][1] = fmaf(a.y, b.y, acc[1][1]);
                acc[1][2] = fmaf(a.y, b.z, acc[1][2]); acc[1][3] = fmaf(a.y, b.w, acc[1][3]);
                acc[2][0] = fmaf(a.z, b.x, acc[2][0]); acc[2][1] = fmaf(a.z, b.y, acc[2][1]);
                acc[2][2] = fmaf(a.z, b.z, acc[2][2]); acc[2][3] = fmaf(a.z, b.w, acc[2][3]);
                acc[3][0] = fmaf(a.w, b.x, acc[3][0]); acc[3][1] = fmaf(a.w, b.y, acc[3][1]);
                acc[3][2] = fmaf(a.w, b.z, acc[3][2]); acc[3][3] = fmaf(a.w, b.w, acc[3][3]);
            }
            __syncthreads();
        }
#pragma unroll
        for (int i = 0; i < 4; ++i) {
            int row = rowBase + (tm << 2) + i;
            int rc  = (row < M) ? row : M - 1;
#pragma unroll
            for (int j = 0; j < 4; ++j) {
                int col = (tn << 2) + j;
                float v = acc[i][j] + UX[(size_t)rc * 256 + 128 + col];
                ts[(tm << 2) + i][col] = fmaxf(v, 0.f);
            }
        }
    }

    // ---- phase 2: UX2 = ts @ WH + bias ----
    {
        int tm = tid >> 5, tn = tid & 31;   // rows 4*tm, cols 8*tn
        float acc[4][8] = {};
        for (int k0 = 0; k0 < 128; k0 += 16) {
#pragma unroll
            for (int q = 0; q < 4; ++q) {
                int slot = (q << 8) + tid;
                int kr = slot >> 6, c4 = (slot & 63) << 2;
                *(float4*)&Bs[kr][c4] = *(const float4*)(WH + (size_t)(k0 + kr) * 256 + c4);
            }
            __syncthreads();   // also orders ts writes (phase1) before ts reads
#pragma unroll
            for (int k = 0; k < 16; ++k) {
                float4 b0 = *(const float4*)&Bs[k][tn << 3];
                float4 b1 = *(const float4*)&Bs[k][(tn << 3) + 4];
                float br[8] = {b0.x, b0.y, b0.z, b0.w, b1.x, b1.y, b1.z, b1.w};
#pragma unroll
                for (int i = 0; i < 4; ++i) {
                    float a = ts[(tm << 2) + i][k0 + k];
#pragma unroll
                    for (int j = 0; j < 8; ++j)
                        acc[i][j] = fmaf(a, br[j], acc[i][j]);
                }
            }
            __syncthreads();
        }
        bool half = (tn >= 16);
        const float* bias = half ? bx2 : bu2;
#pragma unroll
        for (int i = 0; i < 4; ++i) {
            int row = rowBase + (tm << 2) + i;
            if (row >= M) continue;
            float rm = rmask[(tm << 2) + i];
            float4 o0, o1;
            float* po0 = (float*)&o0; float* po1 = (float*)&o1;
#pragma unroll
            for (int j = 0; j < 4; ++j) {
                int gcol0 = (tn << 3) + j, gcol1 = (tn << 3) + 4 + j;
                int cj0 = gcol0 & 127, cj1 = gcol1 & 127;
                float v0 = acc[i][j] + bias[cj0];
                float v1s = acc[i][4 + j] + bias[cj1];
                if (half) { v0 = fmaf(rm, v2[cj0], v0); v1s = fmaf(rm, v2[cj1], v1s); }
                po0[j] = v0; po1[j] = v1s;
            }
            float* orow = UX2 + (size_t)row * 256 + (tn << 3);
            *(float4*)(orow)     = o0;
            *(float4*)(orow + 4) = o1;
        }
    }
}

// ---------------------------------------------------------------------------
// fused_last: phase0 (LDS-staged edges) + z2 = relu(xn2 + mh@M2) + proj
// ---------------------------------------------------------------------------
__global__ __launch_bounds__(256)
void fused_last_kernel(const float* __restrict__ UX2, const float* __restrict__ wlast,
                       const float* __restrict__ eas, const int* __restrict__ eoff,
                       const int* __restrict__ cnt,
                       const float* __restrict__ Mmat,
                       const float* __restrict__ w2, const float* __restrict__ b2,
                       float* __restrict__ proj, int M) {
    __shared__ float mhT[128][36];
    __shared__ float Bs[16][132];
    __shared__ float ebuf[1536];
    int rowBase = blockIdx.x * 32;
    int tid = threadIdx.x;

    {
        int d = tid & 127, sub = tid >> 7;
        float w = wlast[d];
        float uu[16], sum[16];
        int es[16], ec[16];
#pragma unroll
        for (int it = 0; it < 16; ++it) {
            int n  = rowBase + it * 2 + sub;
            int nc = (n < M) ? n : M - 1;
            ec[it] = cnt[nc];
            es[it] = eoff[nc];
            uu[it] = UX2[(size_t)nc * 256 + d];
            sum[it] = 0.f;
        }
        int ebase = eoff[rowBase];
        int eend  = (rowBase + 32 < M) ? eoff[rowBase + 32] : E_EDGES;
        for (int w0 = ebase; w0 < eend; w0 += 1536) {
            int wlen = min(1536, eend - w0);
            __syncthreads();
            for (int q = tid; q < wlen; q += 256) ebuf[q] = eas[w0 + q];
            __syncthreads();
#pragma unroll
            for (int it = 0; it < 16; ++it) {
                int lo = max(es[it], w0), hi = min(es[it] + ec[it], w0 + wlen);
                for (int e = lo; e < hi; ++e)
                    sum[it] += fmaxf(fmaf(ebuf[e - w0], w, uu[it]), 0.f);
            }
        }
#pragma unroll
        for (int it = 0; it < 16; ++it)
            mhT[d][it * 2 + sub] = (ec[it] > 0) ? sum[it] / (float)ec[it] : 0.f;
    }
    __syncthreads();

    int tm = tid >> 5, tn = tid & 31;
    float acc[4][4] = {};
    for (int k0 = 0; k0 < 128; k0 += 16) {
#pragma unroll
        for (int t2 = 0; t2 < 2; ++t2) {
            int f2 = (tid << 1) | t2;
            int kr = f2 >> 5, c4 = (f2 & 31) << 2;
            *(float4*)&Bs[kr][c4] = *(const float4*)(Mmat + (size_t)(k0 + kr) * 128 + c4);
        }
        __syncthreads();
#pragma unroll
        for (int k = 0; k < 16; ++k) {
            float4 a = *(const float4*)&mhT[k0 + k][tm << 2];
            float4 b = *(const float4*)&Bs[k][tn << 2];
            acc[0][0] = fmaf(a.x, b.x, acc[0][0]); acc[0][1] = fmaf(a.x, b.y, acc[0][1]);
            acc[0][2] = fmaf(a.x, b.z, acc[0][2]); acc[0][3] = fmaf(a.x, b.w, acc[0][3]);
            acc[1][0] = fmaf(a.y, b.x, acc[1][0]); acc[1][1] = fmaf(a.y, b.y, acc[1][1]);
            acc[1][2] = fmaf(a.y, b.z, acc[1][2]); acc[1][3] = fmaf(a.y, b.w, acc[1][3]);
            acc[2][0] = fmaf(a.z, b.x, acc[2][0]); acc[2][1] = fmaf(a.z, b.y, acc[2][1]);
            acc[2][2] = fmaf(a.z, b.z, acc[2][2]); acc[2][3] = fmaf(a.z, b.w, acc[2][3]);
            acc[3][0] = fmaf(a.w, b.x, acc[3][0]); acc[3][1] = fmaf(a.w, b.y, acc[3][1]);
            acc[3][2] = fmaf(a.w, b.z, acc[3][2]); acc[3][3] = fmaf(a.w, b.w, acc[3][3]);
        }
        __syncthreads();
    }

    float p0[4] = {}, p1[4] = {};
#pragma unroll
    for (int i = 0; i < 4; ++i) {
        int row = rowBase + (tm << 2) + i;
        int rc  = (row < M) ? row : M - 1;
#pragma unroll
        for (int j = 0; j < 4; ++j) {
            int col = (tn << 2) + j;
            float t = fmaxf(acc[i][j] + UX2[(size_t)rc * 256 + 128 + col], 0.f);
            p0[i] = fmaf(t, w2[col * 2],     p0[i]);
            p1[i] = fmaf(t, w2[col * 2 + 1], p1[i]);
        }
    }
#pragma unroll
    for (int i = 0; i < 4; ++i) {
        for (int off = 16; off > 0; off >>= 1) {
            p0[i] += __shfl_xor(p0[i], off, 64);
            p1[i] += __shfl_xor(p1[i], off, 64);
        }
    }
    if (tn == 0) {
#pragma unroll
        for (int i = 0; i < 4; ++i) {
            int row = rowBase + (tm << 2) + i;
            if (row < M) {
                proj[row * 2]     = p0[i] + b2[0];
                proj[row * 2 + 1] = p1[i] + b2[1];
            }
        }
    }
}

__global__ void dist_kernel(const float* __restrict__ proj, const int* __restrict__ idxs,
                            float* __restrict__ out, int e) {
    int i = blockIdx.x * blockDim.x + threadIdx.x;
    if (i >= e) return;
    int n = i / KNB;
    int m = idxs[i];
    float dx = proj[2 * n] - proj[2 * m];
    float dy = proj[2 * n + 1] - proj[2 * m + 1];
    out[i] = dx * dx + dy * dy;
}

// ---------------------------------------------------------------------------
extern "C" void kernel_launch(void* const* d_in, const int* in_sizes, int n_in,
                              void* d_out, int out_size, void* d_ws, size_t ws_size,
                              hipStream_t stream) {
    (void)in_sizes; (void)n_in; (void)out_size; (void)ws_size;
    const float* x    = (const float*)d_in[0];
    const float* eatt = (const float*)d_in[1];
    const int*   idxs = (const int*)d_in[2];
    const float* mw1  = (const float*)d_in[3];
    const float* mb1  = (const float*)d_in[4];
    const float* mw2  = (const float*)d_in[5];
    const float* mb2  = (const float*)d_in[6];
    const float* nw1  = (const float*)d_in[7];
    const float* nb1  = (const float*)d_in[8];
    const float* nw2  = (const float*)d_in[9];
    const float* nb2  = (const float*)d_in[10];
    const float* m2w1 = (const float*)d_in[11];
    const float* m2b1 = (const float*)d_in[12];
    const float* m2w2 = (const float*)d_in[13];
    const float* m2b2 = (const float*)d_in[14];
    const float* n2w1 = (const float*)d_in[15];
    const float* n2b1 = (const float*)d_in[16];
    const float* n2w2 = (const float*)d_in[17];
    const float* n2b2 = (const float*)d_in[18];
    float* out = (float*)d_out;

    float* fws   = (float*)d_ws;
    float* UX1   = fws;                   // 10000*256
    float* UX2   = fws + 2560000;         // 10000*256
    float* proj  = fws + 5120000;         // 10000*2
    float* maskv = fws + 5140000;         // 10000
    float* eas   = fws + 5150016;         // 150000
    float* M1    = fws + 5300016;         // 128*128
    float* M2    = fws + 5316400;         // 128*128
    float* WH    = fws + 5332784;         // 128*256
    float* v1    = fws + 5365552;         // 128
    float* v2    = fws + 5365680;         // 128
    float* bu2   = fws + 5365808;         // 128
    float* bx2   = fws + 5365936;         // 128
    int*   cnt   = (int*)(fws + 5366064);
    int*   fillc = cnt + N_NODES;
    int*   eoff  = fillc + N_NODES;

    // L1: CSR histogram+scan (block 0) + all weight folds (blocks 1..40)
    scanfold_kernel<<<41, 256, 0, stream>>>(idxs,
                                            mw2, mb2, nw1, nb2, nw2,
                                            m2w1, m2b1, m2w2, m2b2, n2w1, n2b1,
                                            M1, M2, WH, v1, v2, bu2, bx2,
                                            cnt, eoff, maskv, fillc);

    // L2: CSR fill (587 blocks) + UX1 = [x@mw1+mb1 | x@nw1+nb1+maskv*v1] (628 blocks)
    fillgemm_kernel<<<FILL_BLOCKS + GEMM_BLOCKS, 256, 0, stream>>>(
        idxs, eatt, eoff, fillc, eas,
        x, mw1, nw1, mb1, nb1, v1, maskv, UX1, N_NODES);

    // L3: layer 1 msg-mean + z1 + layer-2 input projection
    fused_mid_kernel<<<313, 256, 0, stream>>>(UX1, mw1 + 784 * 128, eas, eoff, cnt,
                                              M1, WH, bu2, bx2, v2, UX2, N_NODES);

    // L4: layer 2 msg-mean + z2 + proj
    fused_last_kernel<<<313, 256, 0, stream>>>(UX2, m2w1 + 128 * 128, eas, eoff, cnt,
                                               M2, n2w2, n2b2, proj, N_NODES);

    // L5: per-edge squared distances
    dist_kernel<<<FILL_BLOCKS, 256, 0, stream>>>(proj, idxs, out, E_EDGES);
}

// Round 8
// 302.810 us; speedup vs baseline: 1.4282x; 1.4282x over previous
//
#include <hip/hip_runtime.h>

#define N_NODES 10000
#define E_EDGES 150000
#define KNB     15
#define FILL_BLOCKS 587   // ceil(E/256)
#define GEMM_BLOCKS 628   // 157 rowBlks x 4 colBlks

// ---------------------------------------------------------------------------
// CSR count: parallel global atomics (587 blocks) — NEVER single-block this.
// ---------------------------------------------------------------------------
__global__ void count_kernel(const int* __restrict__ idxs, int* __restrict__ cnt, int e) {
    int i = blockIdx.x * blockDim.x + threadIdx.x;
    if (i < e) atomicAdd(&cnt[idxs[i]], 1);
}

// ---------------------------------------------------------------------------
// gemm_tile2 (MR=2) — weight-space folds only
// ---------------------------------------------------------------------------
__device__ __forceinline__
void gemm_tile2(const float* __restrict__ A, int K,
                const float* __restrict__ Blo, const float* __restrict__ Bhi, int ldB,
                float* __restrict__ C, int ldC, int M,
                int rowBlk, int colBlk) {
    __shared__ float As2[16][34];
    __shared__ float Bs2[16][64];
    int tid = threadIdx.x;
    int tn  = tid & 15, tm = tid >> 4;
    int arow = tid >> 3, acB = (tid & 7) << 1;
    int brow = tid >> 4, bcol = (tid & 15) << 2;
    int rowBase = rowBlk * 32, colBase = colBlk * 64;

    bool half = (Bhi != nullptr) && (colBase >= 128);
    const float* B = half ? Bhi : Blo;
    int bj = colBase - (half ? 128 : 0) + bcol;

    float2 av; float4 bv;
    auto loadA = [&](int k0, float2& dst) {
        int gr = rowBase + arow;
        if (gr < M) dst = *(const float2*)(A + (size_t)gr * K + k0 + acB);
        else { dst.x = dst.y = 0.f; }
    };
    auto loadB = [&](int k0, float4& dst) {
        dst = *(const float4*)(B + (size_t)(k0 + brow) * ldB + bj);
    };
    loadA(0, av); loadB(0, bv);

    float acc[2][4] = {};
    for (int k0 = 0; k0 < K; k0 += 16) {
        __syncthreads();
        As2[acB + 0][arow] = av.x; As2[acB + 1][arow] = av.y;
        *(float4*)&Bs2[brow][bcol] = bv;
        __syncthreads();
        if (k0 + 16 < K) { loadA(k0 + 16, av); loadB(k0 + 16, bv); }
#pragma unroll
        for (int k = 0; k < 16; ++k) {
            float4 b = *(const float4*)&Bs2[k][tn << 2];
            float2 a = *(const float2*)&As2[k][tm << 1];
            acc[0][0] = fmaf(a.x, b.x, acc[0][0]); acc[0][1] = fmaf(a.x, b.y, acc[0][1]);
            acc[0][2] = fmaf(a.x, b.z, acc[0][2]); acc[0][3] = fmaf(a.x, b.w, acc[0][3]);
            acc[1][0] = fmaf(a.y, b.x, acc[1][0]); acc[1][1] = fmaf(a.y, b.y, acc[1][1]);
            acc[1][2] = fmaf(a.y, b.z, acc[1][2]); acc[1][3] = fmaf(a.y, b.w, acc[1][3]);
        }
    }
#pragma unroll
    for (int i = 0; i < 2; ++i) {
        int row = rowBase + tm * 2 + i;
        if (row >= M) continue;
#pragma unroll
        for (int j = 0; j < 4; ++j)
            C[(size_t)row * ldC + colBase + (tn << 2) + j] = acc[i][j];
    }
}

// ---------------------------------------------------------------------------
// Launch 3: block 0 = prefix-scan of global cnt (writes eoff/maskv, zeroes
// fillc); blocks 1..40 = weight folds (M1, M2, WH, v1, v2, bu2, bx2).
// ---------------------------------------------------------------------------
__global__ __launch_bounds__(256)
void scanfold_kernel(const float* __restrict__ mw2, const float* __restrict__ mb2,
                     const float* __restrict__ nw1, const float* __restrict__ nb2,
                     const float* __restrict__ nw2,
                     const float* __restrict__ m2w1, const float* __restrict__ m2b1,
                     const float* __restrict__ m2w2, const float* __restrict__ m2b2,
                     const float* __restrict__ n2w1, const float* __restrict__ n2b1,
                     float* __restrict__ M1, float* __restrict__ M2,
                     float* __restrict__ WH,
                     float* __restrict__ v1, float* __restrict__ v2,
                     float* __restrict__ bu2, float* __restrict__ bx2,
                     const int* __restrict__ cnt, int* __restrict__ eoff,
                     float* __restrict__ maskv, int* __restrict__ fillc) {
    int b = blockIdx.x;
    if (b == 0) {
        __shared__ int ssum[256];
        int tid = threadIdx.x;
        const int CH = 40;                 // 256*40 = 10240 >= N
        int base = tid * CH;
        int v[CH]; int s = 0;
#pragma unroll
        for (int q = 0; q < CH; ++q) {
            int i = base + q;
            v[q] = (i < N_NODES) ? cnt[i] : 0;
            s += v[q];
        }
        ssum[tid] = s;
        __syncthreads();
        for (int off = 1; off < 256; off <<= 1) {
            int t = (tid >= off) ? ssum[tid - off] : 0;
            __syncthreads();
            ssum[tid] += t;
            __syncthreads();
        }
        int ex = ssum[tid] - s;            // exclusive prefix of chunk
#pragma unroll
        for (int q = 0; q < CH; ++q) {
            int i = base + q;
            if (i < N_NODES) {
                eoff[i]  = ex;
                maskv[i] = (v[q] > 0) ? 1.f : 0.f;
                fillc[i] = 0;
                ex += v[q];
            }
        }
        return;
    }
    b -= 1;
    if (b < 8) {
        gemm_tile2(mw2, 784, nw1 + 784 * 128, nullptr, 128, M1, 128, 128, b >> 1, b & 1);
    } else if (b < 16) {
        int t = b - 8;
        gemm_tile2(m2w2, 128, n2w1 + 128 * 128, nullptr, 128, M2, 128, 128, t >> 1, t & 1);
    } else if (b < 32) {
        int t = b - 16;
        gemm_tile2(nw2, 128, m2w1, n2w1, 128, WH, 256, 128, t >> 2, t & 3);
    } else {
        __shared__ float red[256];
        int t  = (b - 32) >> 1;
        int j  = ((b - 32) & 1) * 64 + (threadIdx.x & 63);
        int kq = threadIdx.x >> 6;
        const float* bvec; const float* Bv; const float* add; float* out; int Kv;
        if (t == 0)      { bvec = mb2;  Bv = nw1 + 784 * 128;  add = nullptr; out = v1;  Kv = 784; }
        else if (t == 1) { bvec = m2b2; Bv = n2w1 + 128 * 128; add = nullptr; out = v2;  Kv = 128; }
        else if (t == 2) { bvec = nb2;  Bv = m2w1;             add = m2b1;    out = bu2; Kv = 128; }
        else             { bvec = nb2;  Bv = n2w1;             add = n2b1;    out = bx2; Kv = 128; }
        float acc = 0.f;
        for (int k = kq; k < Kv; k += 4) acc = fmaf(bvec[k], Bv[k * 128 + j], acc);
        red[threadIdx.x] = acc;
        __syncthreads();
        if (threadIdx.x < 64) {
            float tot = red[threadIdx.x] + red[threadIdx.x + 64] +
                        red[threadIdx.x + 128] + red[threadIdx.x + 192];
            out[j] = tot + (add ? add[j] : 0.f);
        }
    }
}

// ---------------------------------------------------------------------------
// gemm784 tile — R3-proven structure: 256 thr, 64x64 tile, 4x4 micro,
// LDS A(transposed, pad 68) + B, register prefetch, 2 barriers/k-tile.
// ---------------------------------------------------------------------------
__device__ __forceinline__
void gemm784_tile(const float* __restrict__ A,
                  const float* __restrict__ B0, const float* __restrict__ B1,
                  const float* __restrict__ biasLo, const float* __restrict__ biasHi,
                  const float* __restrict__ vhi, const float* __restrict__ rowmask,
                  float* __restrict__ C, int M, int gb) {
    __shared__ float As[16][68];
    __shared__ float Bs[16][64];
    int rb = gb >> 2, cb = gb & 3;
    int tid = threadIdx.x;
    int tm = tid >> 4, tn = tid & 15;
    int arow = tid >> 2, ac4 = (tid & 3) << 2;
    int brow = tid >> 4, bc4 = (tid & 15) << 2;
    int rowBase = rb * 64, colBase = cb * 64;
    bool hi = colBase >= 128;
    const float* B    = hi ? B1 : B0;
    const float* bias = hi ? biasHi : biasLo;
    int bj = ((cb & 1) << 6) + bc4;

    int gr = rowBase + arow; if (gr > M - 1) gr = M - 1;   // clamp; stores guarded
    const float* Ap = A + (size_t)gr * 784;

    float4 av, bv;
    av = *(const float4*)(Ap + ac4);
    bv = *(const float4*)(B + (size_t)brow * 128 + bj);

    float acc[4][4] = {};
    for (int k0 = 0; k0 < 784; k0 += 16) {
        __syncthreads();
        As[ac4 + 0][arow] = av.x;
        As[ac4 + 1][arow] = av.y;
        As[ac4 + 2][arow] = av.z;
        As[ac4 + 3][arow] = av.w;
        *(float4*)&Bs[brow][bc4] = bv;
        __syncthreads();
        if (k0 + 16 < 784) {
            av = *(const float4*)(Ap + k0 + 16 + ac4);
            bv = *(const float4*)(B + (size_t)(k0 + 16 + brow) * 128 + bj);
        }
#pragma unroll
        for (int k = 0; k < 16; ++k) {
            float4 a = *(const float4*)&As[k][tm << 2];
            float4 b = *(const float4*)&Bs[k][tn << 2];
            acc[0][0] = fmaf(a.x, b.x, acc[0][0]); acc[0][1] = fmaf(a.x, b.y, acc[0][1]);
            acc[0][2] = fmaf(a.x, b.z, acc[0][2]); acc[0][3] = fmaf(a.x, b.w, acc[0][3]);
            acc[1][0] = fmaf(a.y, b.x, acc[1][0]); acc[1][1] = fmaf(a.y, b.y, acc[1][1]);
            acc[1][2] = fmaf(a.y, b.z, acc[1][2]); acc[1][3] = fmaf(a.y, b.w, acc[1][3]);
            acc[2][0] = fmaf(a.z, b.x, acc[2][0]); acc[2][1] = fmaf(a.z, b.y, acc[2][1]);
            acc[2][2] = fmaf(a.z, b.z, acc[2][2]); acc[2][3] = fmaf(a.z, b.w, acc[2][3]);
            acc[3][0] = fmaf(a.w, b.x, acc[3][0]); acc[3][1] = fmaf(a.w, b.y, acc[3][1]);
            acc[3][2] = fmaf(a.w, b.z, acc[3][2]); acc[3][3] = fmaf(a.w, b.w, acc[3][3]);
        }
    }

#pragma unroll
    for (int i = 0; i < 4; ++i) {
        int row = rowBase + (tm << 2) + i;
        if (row >= M) continue;
        float rm = hi ? rowmask[row] : 0.f;
#pragma unroll
        for (int j = 0; j < 4; ++j) {
            int gcol = colBase + (tn << 2) + j;
            int cj   = gcol & 127;
            float v = acc[i][j] + bias[cj];
            if (hi) v = fmaf(rm, vhi[cj], v);
            C[(size_t)row * 256 + gcol] = v;
        }
    }
}

// ---------------------------------------------------------------------------
// Launch 4: blocks [0,587) CSR fill; blocks [587,1215) gemm784.
// fill's memory-bound atomics overlap gemm's VALU work.
// ---------------------------------------------------------------------------
__global__ __launch_bounds__(256)
void fillgemm_kernel(const int* __restrict__ idxs, const float* __restrict__ ea,
                     const int* __restrict__ eoff, int* __restrict__ fillc,
                     float* __restrict__ eas,
                     const float* __restrict__ A,
                     const float* __restrict__ B0, const float* __restrict__ B1,
                     const float* __restrict__ biasLo, const float* __restrict__ biasHi,
                     const float* __restrict__ vhi, const float* __restrict__ rowmask,
                     float* __restrict__ C, int M) {
    int gb = blockIdx.x;
    if (gb < FILL_BLOCKS) {
        int i = gb * 256 + threadIdx.x;
        if (i < E_EDGES) {
            int s = idxs[i];
            int p = atomicAdd(&fillc[s], 1);
            eas[eoff[s] + p] = ea[i];
        }
        return;
    }
    gemm784_tile(A, B0, B1, biasLo, biasHi, vhi, rowmask, C, M, gb - FILL_BLOCKS);
}

// ---------------------------------------------------------------------------
// fused_mid (grid 313, 32 rows/block):
//  phase0: LDS-staged CSR edge window -> mhT[d][m] = mean_e relu(u + ea*w); rmask
//  phase1: ts[32][128] = relu(xn + mhT @ M1)        (4x4 micro)
//  phase2: UX2[32][256] = ts @ WH + bias (+rm*v2)   (4x8 micro)
// ---------------------------------------------------------------------------
__global__ __launch_bounds__(256)
void fused_mid_kernel(const float* __restrict__ UX, const float* __restrict__ wlast,
                      const float* __restrict__ eas, const int* __restrict__ eoff,
                      const int* __restrict__ cnt,
                      const float* __restrict__ Mmat, const float* __restrict__ WH,
                      const float* __restrict__ bu2, const float* __restrict__ bx2,
                      const float* __restrict__ v2,
                      float* __restrict__ UX2, int M) {
    __shared__ float mhT[128][36];
    __shared__ float ts[32][132];
    __shared__ float Bs[16][264];
    __shared__ float ebuf[1536];
    __shared__ float rmask[32];
    int rowBase = blockIdx.x * 32;
    int tid = threadIdx.x;

    // ---- phase 0 ----
    {
        int d = tid & 127, sub = tid >> 7;
        float w = wlast[d];
        float uu[16], sum[16];
        int es[16], ec[16];
#pragma unroll
        for (int it = 0; it < 16; ++it) {
            int n  = rowBase + it * 2 + sub;
            int nc = (n < M) ? n : M - 1;
            ec[it] = cnt[nc];
            es[it] = eoff[nc];
            uu[it] = UX[(size_t)nc * 256 + d];
            sum[it] = 0.f;
            if (d == 0) rmask[it * 2 + sub] = (ec[it] > 0) ? 1.f : 0.f;
        }
        int ebase = eoff[rowBase];
        int eend  = (rowBase + 32 < M) ? eoff[rowBase + 32] : E_EDGES;
        for (int w0 = ebase; w0 < eend; w0 += 1536) {
            int wlen = min(1536, eend - w0);
            __syncthreads();
            for (int q = tid; q < wlen; q += 256) ebuf[q] = eas[w0 + q];
            __syncthreads();
#pragma unroll
            for (int it = 0; it < 16; ++it) {
                int lo = max(es[it], w0), hi = min(es[it] + ec[it], w0 + wlen);
                for (int e = lo; e < hi; ++e)
                    sum[it] += fmaxf(fmaf(ebuf[e - w0], w, uu[it]), 0.f);
            }
        }
#pragma unroll
        for (int it = 0; it < 16; ++it)
            mhT[d][it * 2 + sub] = (ec[it] > 0) ? sum[it] / (float)ec[it] : 0.f;
    }
    __syncthreads();

    // ---- phase 1: ts = relu(xn + mhT @ Mmat) ----
    {
        int tm = tid >> 5, tn = tid & 31;
        float acc[4][4] = {};
        for (int k0 = 0; k0 < 128; k0 += 16) {
#pragma unroll
            for (int t2 = 0; t2 < 2; ++t2) {
                int f2 = (tid << 1) | t2;
                int kr = f2 >> 5, c4 = (f2 & 31) << 2;
                *(float4*)&Bs[kr][c4] = *(const float4*)(Mmat + (size_t)(k0 + kr) * 128 + c4);
            }
            __syncthreads();
#pragma unroll
            for (int k = 0; k < 16; ++k) {
                float4 a = *(const float4*)&mhT[k0 + k][tm << 2];
                float4 b = *(const float4*)&Bs[k][tn << 2];
                acc[0][0] = fmaf(a.x, b.x, acc[0][0]); acc[0][1] = fmaf(a.x, b.y, acc[0][1]);
                acc[0][2] = fmaf(a.x, b.z, acc[0][2]); acc[0][3] = fmaf(a.x, b.w, acc[0][3]);
                acc[1][0] = fmaf(a.y, b.x, acc[1][0]); acc[1][1] = fmaf(a.y, b.y, acc[1][1]);
                acc[1][2] = fmaf(a.y, b.z, acc[1][2]); acc[1][3] = fmaf(a.y, b.w, acc[1][3]);
                acc[2][0] = fmaf(a.z, b.x, acc[2][0]); acc[2][1] = fmaf(a.z, b.y, acc[2][1]);
                acc[2][2] = fmaf(a.z, b.z, acc[2][2]); acc[2][3] = fmaf(a.z, b.w, acc[2][3]);
                acc[3][0] = fmaf(a.w, b.x, acc[3][0]); acc[3][1] = fmaf(a.w, b.y, acc[3][1]);
                acc[3][2] = fmaf(a.w, b.z, acc[3][2]); acc[3][3] = fmaf(a.w, b.w, acc[3][3]);
            }
            __syncthreads();
        }
#pragma unroll
        for (int i = 0; i < 4; ++i) {
            int row = rowBase + (tm << 2) + i;
            int rc  = (row < M) ? row : M - 1;
#pragma unroll
            for (int j = 0; j < 4; ++j) {
                int col = (tn << 2) + j;
                float v = acc[i][j] + UX[(size_t)rc * 256 + 128 + col];
                ts[(tm << 2) + i][col] = fmaxf(v, 0.f);
            }
        }
    }

    // ---- phase 2: UX2 = ts @ WH + bias ----
    {
        int tm = tid >> 5, tn = tid & 31;   // rows 4*tm, cols 8*tn
        float acc[4][8] = {};
        for (int k0 = 0; k0 < 128; k0 += 16) {
#pragma unroll
            for (int q = 0; q < 4; ++q) {
                int slot = (q << 8) + tid;
                int kr = slot >> 6, c4 = (slot & 63) << 2;
                *(float4*)&Bs[kr][c4] = *(const float4*)(WH + (size_t)(k0 + kr) * 256 + c4);
            }
            __syncthreads();   // also orders ts writes (phase1) before ts reads
#pragma unroll
            for (int k = 0; k < 16; ++k) {
                float4 b0 = *(const float4*)&Bs[k][tn << 3];
                float4 b1 = *(const float4*)&Bs[k][(tn << 3) + 4];
                float br[8] = {b0.x, b0.y, b0.z, b0.w, b1.x, b1.y, b1.z, b1.w};
#pragma unroll
                for (int i = 0; i < 4; ++i) {
                    float a = ts[(tm << 2) + i][k0 + k];
#pragma unroll
                    for (int j = 0; j < 8; ++j)
                        acc[i][j] = fmaf(a, br[j], acc[i][j]);
                }
            }
            __syncthreads();
        }
        bool half = (tn >= 16);
        const float* bias = half ? bx2 : bu2;
#pragma unroll
        for (int i = 0; i < 4; ++i) {
            int row = rowBase + (tm << 2) + i;
            if (row >= M) continue;
            float rm = rmask[(tm << 2) + i];
            float4 o0, o1;
            float* po0 = (float*)&o0; float* po1 = (float*)&o1;
#pragma unroll
            for (int j = 0; j < 4; ++j) {
                int gcol0 = (tn << 3) + j, gcol1 = (tn << 3) + 4 + j;
                int cj0 = gcol0 & 127, cj1 = gcol1 & 127;
                float v0 = acc[i][j] + bias[cj0];
                float v1s = acc[i][4 + j] + bias[cj1];
                if (half) { v0 = fmaf(rm, v2[cj0], v0); v1s = fmaf(rm, v2[cj1], v1s); }
                po0[j] = v0; po1[j] = v1s;
            }
            float* orow = UX2 + (size_t)row * 256 + (tn << 3);
            *(float4*)(orow)     = o0;
            *(float4*)(orow + 4) = o1;
        }
    }
}

// ---------------------------------------------------------------------------
// fused_last: phase0 (LDS-staged edges) + z2 = relu(xn2 + mh@M2) + proj
// ---------------------------------------------------------------------------
__global__ __launch_bounds__(256)
void fused_last_kernel(const float* __restrict__ UX2, const float* __restrict__ wlast,
                       const float* __restrict__ eas, const int* __restrict__ eoff,
                       const int* __restrict__ cnt,
                       const float* __restrict__ Mmat,
                       const float* __restrict__ w2, const float* __restrict__ b2,
                       float* __restrict__ proj, int M) {
    __shared__ float mhT[128][36];
    __shared__ float Bs[16][132];
    __shared__ float ebuf[1536];
    int rowBase = blockIdx.x * 32;
    int tid = threadIdx.x;

    {
        int d = tid & 127, sub = tid >> 7;
        float w = wlast[d];
        float uu[16], sum[16];
        int es[16], ec[16];
#pragma unroll
        for (int it = 0; it < 16; ++it) {
            int n  = rowBase + it * 2 + sub;
            int nc = (n < M) ? n : M - 1;
            ec[it] = cnt[nc];
            es[it] = eoff[nc];
            uu[it] = UX2[(size_t)nc * 256 + d];
            sum[it] = 0.f;
        }
        int ebase = eoff[rowBase];
        int eend  = (rowBase + 32 < M) ? eoff[rowBase + 32] : E_EDGES;
        for (int w0 = ebase; w0 < eend; w0 += 1536) {
            int wlen = min(1536, eend - w0);
            __syncthreads();
            for (int q = tid; q < wlen; q += 256) ebuf[q] = eas[w0 + q];
            __syncthreads();
#pragma unroll
            for (int it = 0; it < 16; ++it) {
                int lo = max(es[it], w0), hi = min(es[it] + ec[it], w0 + wlen);
                for (int e = lo; e < hi; ++e)
                    sum[it] += fmaxf(fmaf(ebuf[e - w0], w, uu[it]), 0.f);
            }
        }
#pragma unroll
        for (int it = 0; it < 16; ++it)
            mhT[d][it * 2 + sub] = (ec[it] > 0) ? sum[it] / (float)ec[it] : 0.f;
    }
    __syncthreads();

    int tm = tid >> 5, tn = tid & 31;
    float acc[4][4] = {};
    for (int k0 = 0; k0 < 128; k0 += 16) {
#pragma unroll
        for (int t2 = 0; t2 < 2; ++t2) {
            int f2 = (tid << 1) | t2;
            int kr = f2 >> 5, c4 = (f2 & 31) << 2;
            *(float4*)&Bs[kr][c4] = *(const float4*)(Mmat + (size_t)(k0 + kr) * 128 + c4);
        }
        __syncthreads();
#pragma unroll
        for (int k = 0; k < 16; ++k) {
            float4 a = *(const float4*)&mhT[k0 + k][tm << 2];
            float4 b = *(const float4*)&Bs[k][tn << 2];
            acc[0][0] = fmaf(a.x, b.x, acc[0][0]); acc[0][1] = fmaf(a.x, b.y, acc[0][1]);
            acc[0][2] = fmaf(a.x, b.z, acc[0][2]); acc[0][3] = fmaf(a.x, b.w, acc[0][3]);
            acc[1][0] = fmaf(a.y, b.x, acc[1][0]); acc[1][1] = fmaf(a.y, b.y, acc[1][1]);
            acc[1][2] = fmaf(a.y, b.z, acc[1][2]); acc[1][3] = fmaf(a.y, b.w, acc[1][3]);
            acc[2][0] = fmaf(a.z, b.x, acc[2][0]); acc[2][1] = fmaf(a.z, b.y, acc[2][1]);
            acc[2][2] = fmaf(a.z, b.z, acc[2][2]); acc[2][3] = fmaf(a.z, b.w, acc[2][3]);
            acc[3][0] = fmaf(a.w, b.x, acc[3][0]); acc[3][1] = fmaf(a.w, b.y, acc[3][1]);
            acc[3][2] = fmaf(a.w, b.z, acc[3][2]); acc[3][3] = fmaf(a.w, b.w, acc[3][3]);
        }
        __syncthreads();
    }

    float p0[4] = {}, p1[4] = {};
#pragma unroll
    for (int i = 0; i < 4; ++i) {
        int row = rowBase + (tm << 2) + i;
        int rc  = (row < M) ? row : M - 1;
#pragma unroll
        for (int j = 0; j < 4; ++j) {
            int col = (tn << 2) + j;
            float t = fmaxf(acc[i][j] + UX2[(size_t)rc * 256 + 128 + col], 0.f);
            p0[i] = fmaf(t, w2[col * 2],     p0[i]);
            p1[i] = fmaf(t, w2[col * 2 + 1], p1[i]);
        }
    }
#pragma unroll
    for (int i = 0; i < 4; ++i) {
        for (int off = 16; off > 0; off >>= 1) {
            p0[i] += __shfl_xor(p0[i], off, 64);
            p1[i] += __shfl_xor(p1[i], off, 64);
        }
    }
    if (tn == 0) {
#pragma unroll
        for (int i = 0; i < 4; ++i) {
            int row = rowBase + (tm << 2) + i;
            if (row < M) {
                proj[row * 2]     = p0[i] + b2[0];
                proj[row * 2 + 1] = p1[i] + b2[1];
            }
        }
    }
}

__global__ void dist_kernel(const float* __restrict__ proj, const int* __restrict__ idxs,
                            float* __restrict__ out, int e) {
    int i = blockIdx.x * blockDim.x + threadIdx.x;
    if (i >= e) return;
    int n = i / KNB;
    int m = idxs[i];
    float2 pn = *(const float2*)(proj + 2 * n);
    float2 pm = *(const float2*)(proj + 2 * m);
    float dx = pn.x - pm.x;
    float dy = pn.y - pm.y;
    out[i] = dx * dx + dy * dy;
}

// ---------------------------------------------------------------------------
extern "C" void kernel_launch(void* const* d_in, const int* in_sizes, int n_in,
                              void* d_out, int out_size, void* d_ws, size_t ws_size,
                              hipStream_t stream) {
    (void)in_sizes; (void)n_in; (void)out_size; (void)ws_size;
    const float* x    = (const float*)d_in[0];
    const float* eatt = (const float*)d_in[1];
    const int*   idxs = (const int*)d_in[2];
    const float* mw1  = (const float*)d_in[3];
    const float* mb1  = (const float*)d_in[4];
    const float* mw2  = (const float*)d_in[5];
    const float* mb2  = (const float*)d_in[6];
    const float* nw1  = (const float*)d_in[7];
    const float* nb1  = (const float*)d_in[8];
    const float* nw2  = (const float*)d_in[9];
    const float* nb2  = (const float*)d_in[10];
    const float* m2w1 = (const float*)d_in[11];
    const float* m2b1 = (const float*)d_in[12];
    const float* m2w2 = (const float*)d_in[13];
    const float* m2b2 = (const float*)d_in[14];
    const float* n2w1 = (const float*)d_in[15];
    const float* n2b1 = (const float*)d_in[16];
    const float* n2w2 = (const float*)d_in[17];
    const float* n2b2 = (const float*)d_in[18];
    float* out = (float*)d_out;

    float* fws   = (float*)d_ws;
    float* UX1   = fws;                   // 10000*256
    float* UX2   = fws + 2560000;         // 10000*256
    float* proj  = fws + 5120000;         // 10000*2
    float* maskv = fws + 5140000;         // 10000
    float* eas   = fws + 5150016;         // 150000
    float* M1    = fws + 5300016;         // 128*128
    float* M2    = fws + 5316400;         // 128*128
    float* WH    = fws + 5332784;         // 128*256
    float* v1    = fws + 5365552;         // 128
    float* v2    = fws + 5365680;         // 128
    float* bu2   = fws + 5365808;         // 128
    float* bx2   = fws + 5365936;         // 128
    int*   cnt   = (int*)(fws + 5366064);
    int*   fillc = cnt + N_NODES;
    int*   eoff  = fillc + N_NODES;

    // L1-2: zero cnt, parallel histogram (global atomics)
    hipMemsetAsync(cnt, 0, N_NODES * sizeof(int), stream);
    count_kernel<<<FILL_BLOCKS, 256, 0, stream>>>(idxs, cnt, E_EDGES);

    // L3: prefix-scan of cnt (block 0, zeroes fillc) + all weight folds
    scanfold_kernel<<<41, 256, 0, stream>>>(mw2, mb2, nw1, nb2, nw2,
                                            m2w1, m2b1, m2w2, m2b2, n2w1, n2b1,
                                            M1, M2, WH, v1, v2, bu2, bx2,
                                            cnt, eoff, maskv, fillc);

    // L4: CSR fill (587 blocks) + UX1 = [x@mw1+mb1 | x@nw1+nb1+maskv*v1] (628 blocks)
    fillgemm_kernel<<<FILL_BLOCKS + GEMM_BLOCKS, 256, 0, stream>>>(
        idxs, eatt, eoff, fillc, eas,
        x, mw1, nw1, mb1, nb1, v1, maskv, UX1, N_NODES);

    // L5: layer 1 msg-mean + z1 + layer-2 input projection
    fused_mid_kernel<<<313, 256, 0, stream>>>(UX1, mw1 + 784 * 128, eas, eoff, cnt,
                                              M1, WH, bu2, bx2, v2, UX2, N_NODES);

    // L6: layer 2 msg-mean + z2 + proj
    fused_last_kernel<<<313, 256, 0, stream>>>(UX2, m2w1 + 128 * 128, eas, eoff, cnt,
                                               M2, n2w2, n2b2, proj, N_NODES);

    // L7: per-edge squared distances
    dist_kernel<<<FILL_BLOCKS, 256, 0, stream>>>(proj, idxs, out, E_EDGES);
}